// Round 11
// baseline (78.256 us; speedup 1.0000x reference)
//
#include <hip/hip_runtime.h>
#include <hip/hip_fp16.h>

#define WIDTH   256
#define HEIGHT  256
#define NG      8192
#define TILE_SZ 16
#define MINW    1e-6f
#define BLK     1024
#define NBATCH  (NG / BLK)      // 8
#define NWAVE   (BLK / 64)      // 16
#define NSEG    16              // depth segments (one per wave)
#define RSZ     512             // gaussians staged per round
#define KC      (-0.72134752044f)   // -0.5 * log2(e)

// Fused kernel: cull + pack + depth-split composite. 1 block per tile.
// VGPR cap 128 (bounds 1024,4): R10 proved the 64-cap (8 waves/SIMD) spills
// and regresses; 4 waves/SIMD with clean registers is the sweet spot here.
__global__ __launch_bounds__(BLK, 4) void raster_kernel(
    const float* __restrict__ pts,    // [N,2]
    const float* __restrict__ icov,   // [N,2,2]
    const float* __restrict__ rad,    // [N]
    const float* __restrict__ cols,   // [N,3]
    const float* __restrict__ opac,   // [N] logits
    float* __restrict__ out)          // [W,H,3]
{
    __shared__ unsigned long long s_ball[NBATCH * NWAVE];   // 1 KB
    __shared__ int s_pfx[NBATCH * NWAVE];                   // 0.5 KB
    __shared__ __align__(16) char s_pool[32768];            // 32 KB
    unsigned short* s_list = (unsigned short*)s_pool;       // 16 KB ordered ids
    float4* s_g = (float4*)(s_pool + 16384);                // 16 KB staged chunk
    float*  pool = (float*)s_pool;                          // 24 KB reduce (after)
    __shared__ float s_P[NSEG][256];                        // 16 KB seg products

    const int tid  = threadIdx.x;
    const int lane = tid & 63;
    const int wave = tid >> 6;
    const int seg  = wave;            // 0..15
    const float tx0 = (float)(blockIdx.x * TILE_SZ);
    const float ty0 = (float)(blockIdx.y * TILE_SZ);
    const float tx1 = tx0 + (float)TILE_SZ;
    const float ty1 = ty0 + (float)TILE_SZ;

    // ---- Phase 1: prefetch all batches, then ballot + wave-0 scan
    float2 pp[NBATCH]; float rr[NBATCH];
    #pragma unroll
    for (int b = 0; b < NBATCH; ++b) {
        pp[b] = ((const float2*)pts)[b * BLK + tid];
        rr[b] = rad[b * BLK + tid];
    }
    unsigned int hitbits = 0;
    #pragma unroll
    for (int b = 0; b < NBATCH; ++b) {
        bool hit = (floorf(pp[b].x - rr[b]) <= tx1) & (ceilf(pp[b].x + rr[b]) >= tx0)
                 & (floorf(pp[b].y - rr[b]) <= ty1) & (ceilf(pp[b].y + rr[b]) >= ty0);
        unsigned long long m = __ballot(hit);
        if (lane == 0) s_ball[b * NWAVE + wave] = m;
        if (hit) hitbits |= (1u << b);
    }
    __syncthreads();
    if (wave == 0) {                  // 128-elem inclusive scan in one wave
        int v0 = __popcll(s_ball[lane]);
        int v1 = __popcll(s_ball[64 + lane]);
        #pragma unroll
        for (int d = 1; d < 64; d <<= 1) {
            const int t0 = __shfl_up(v0, d);
            const int t1 = __shfl_up(v1, d);
            if (lane >= d) { v0 += t0; v1 += t1; }
        }
        s_pfx[lane] = v0;
        s_pfx[64 + lane] = v1 + __shfl(v0, 63);
    }
    __syncthreads();
    const int count = s_pfx[127];
    {
        unsigned int hb = hitbits;
        const unsigned long long ltmask = (1ull << lane) - 1ull;
        while (hb) {
            const int b = __ffs(hb) - 1;  hb &= hb - 1;
            const int idx = b * NWAVE + wave;
            const unsigned long long m = s_ball[idx];
            const int bs = idx ? s_pfx[idx - 1] : 0;
            s_list[bs + __popcll(m & ltmask)] = (unsigned short)(b * BLK + tid);
        }
    }
    __syncthreads();

    // ---- Phase 2: 16 depth segments x 64 quads (2x2 px per thread)
    const int q  = tid & 63;
    const int qx = q >> 3, qy = q & 7;
    const float fx = tx0 + (float)(2 * qx);   // pixel A x; B = +1
    const float fy = ty0 + (float)(2 * qy);   // pixel A y; B = +1
    const int p0 = (2 * qx) * 16 + 2 * qy;
    const int pxi[4] = {p0, p0 + 1, p0 + 16, p0 + 17};
    float Tpx = 1.0f;                          // per-pixel T, owner threads (tid<256)
    float acc[3][4];
    #pragma unroll
    for (int c = 0; c < 3; ++c)
        #pragma unroll
        for (int k = 0; k < 4; ++k) acc[c][k] = 0.0f;

    for (int base = 0; base < count; base += RSZ) {
        const int n = min(RSZ, count - base);
        if (tid < n) {                // inline pack (was prep_kernel)
            const int g = s_list[base + tid];
            const float2 p = ((const float2*)pts)[g];
            const float4 ic = ((const float4*)icov)[g];
            const float op = 1.0f / (1.0f + __expf(-opac[g]));
            const __half2 h = __floats2half2_rn(cols[3 * g], cols[3 * g + 1]);
            unsigned rgbits; __builtin_memcpy(&rgbits, &h, 4);
            s_g[tid * 2 + 0] = make_float4(p.x, p.y, KC * ic.x, 2.0f * KC * ic.y);
            s_g[tid * 2 + 1] = make_float4(KC * ic.w, op, __uint_as_float(rgbits),
                                           cols[3 * g + 2]);
        }
        __syncthreads();

        const int L  = (n + NSEG - 1) >> 4;
        const int i0 = seg * L;
        const int i1 = min(i0 + L, n);

        float P[4] = {1.f, 1.f, 1.f, 1.f};
        float l[3][4];
        #pragma unroll
        for (int c = 0; c < 3; ++c)
            #pragma unroll
            for (int k = 0; k < 4; ++k) l[c][k] = 0.0f;

        #pragma unroll 2
        for (int i = i0; i < i1; ++i) {
            const float4 g0 = s_g[i * 2 + 0];
            const float4 g1 = s_g[i * 2 + 1];
            const float dya = fy - g0.y,  dyb = dya + 1.0f;
            const float dxa = fx - g0.x,  dxb = dxa + 1.0f;
            const float bya = g0.w * dya, byb = g0.w * dyb;
            const float cya = (g1.x * dya) * dya, cyb = (g1.x * dyb) * dyb;
            const float axa = (g0.z * dxa) * dxa, axb = (g0.z * dxb) * dxb;
            const unsigned rgbits = __float_as_uint(g1.z);
            __half2 h; __builtin_memcpy(&h, &rgbits, 4);
            const float2 rg = __half22float2(h);
            const float qv[4] = { fmaf(dxa, bya, axa + cya),
                                  fmaf(dxa, byb, axa + cyb),
                                  fmaf(dxb, bya, axb + cya),
                                  fmaf(dxb, byb, axb + cyb) };
            #pragma unroll
            for (int k = 0; k < 4; ++k) {
                const float a = g1.y * __builtin_amdgcn_exp2f(qv[k]);
                const float w = P[k] * a;
                l[0][k] = fmaf(w, rg.x, l[0][k]);
                l[1][k] = fmaf(w, rg.y, l[1][k]);
                l[2][k] = fmaf(w, g1.w, l[2][k]);
                P[k] = fmaf(-a, P[k], P[k]);
            }
        }
        #pragma unroll
        for (int k = 0; k < 4; ++k) s_P[seg][pxi[k]] = P[k];
        __syncthreads();

        // owner threads: in-place exclusive prefix (Tin per segment) over 16 P's
        if (tid < 256) {
            float run = Tpx;
            #pragma unroll
            for (int s = 0; s < NSEG; ++s) {
                const float Pv = s_P[s][tid];
                s_P[s][tid] = run;            // Tin for segment s
                run *= Pv;
            }
            Tpx = run;
        }
        __syncthreads();

        float Tin[4];
        bool gated[4]; bool anyg = false;
        #pragma unroll
        for (int k = 0; k < 4; ++k) {
            Tin[k] = s_P[seg][pxi[k]];
            const bool alive = (Tin[k] >= MINW);
            gated[k] = alive && (Tin[k] * P[k] < MINW);  // T crossed in this seg
            if (alive && !gated[k]) {
                acc[0][k] = fmaf(Tin[k], l[0][k], acc[0][k]);
                acc[1][k] = fmaf(Tin[k], l[1][k], acc[1][k]);
                acc[2][k] = fmaf(Tin[k], l[2][k], acc[2][k]);
            }
            anyg |= gated[k];
        }
        if (__ballot(anyg) != 0ull) {         // rare: once per pixel lifetime
            float Tl[4] = {Tin[0], Tin[1], Tin[2], Tin[3]};
            for (int i = i0; i < i1; ++i) {
                const float4 g0 = s_g[i * 2 + 0];
                const float4 g1 = s_g[i * 2 + 1];
                const float dya = fy - g0.y,  dyb = dya + 1.0f;
                const float dxa = fx - g0.x,  dxb = dxa + 1.0f;
                const float bya = g0.w * dya, byb = g0.w * dyb;
                const float cya = (g1.x * dya) * dya, cyb = (g1.x * dyb) * dyb;
                const float axa = (g0.z * dxa) * dxa, axb = (g0.z * dxb) * dxb;
                const unsigned rgbits = __float_as_uint(g1.z);
                __half2 h; __builtin_memcpy(&h, &rgbits, 4);
                const float2 rg = __half22float2(h);
                const float qv[4] = { fmaf(dxa, bya, axa + cya),
                                      fmaf(dxa, byb, axa + cyb),
                                      fmaf(dxb, bya, axb + cya),
                                      fmaf(dxb, byb, axb + cyb) };
                #pragma unroll
                for (int k = 0; k < 4; ++k) {
                    const float a  = g1.y * __builtin_amdgcn_exp2f(qv[k]);
                    const float Tn = Tl[k] * (1.0f - a);
                    const float w  = (gated[k] && Tn >= MINW) ? Tl[k] * a : 0.0f;
                    acc[0][k] = fmaf(w, rg.x, acc[0][k]);
                    acc[1][k] = fmaf(w, rg.y, acc[1][k]);
                    acc[2][k] = fmaf(w, g1.w, acc[2][k]);
                    Tl[k] = Tn;
                }
            }
        }
        if (base + RSZ < count) {             // skip barrier on final round
            const bool mydead = (tid < 256) ? (Tpx < MINW) : true;
            if (__syncthreads_count(mydead) == BLK) break;
        }
    }
    __syncthreads();                          // all waves done with s_g/s_list

    // ---- Reduce: fold 16 segments -> 8 slots in pool, then sum 8
    if (seg < 8) {
        #pragma unroll
        for (int k = 0; k < 4; ++k) {
            pool[(seg * 256 + pxi[k]) * 3 + 0] = acc[0][k];
            pool[(seg * 256 + pxi[k]) * 3 + 1] = acc[1][k];
            pool[(seg * 256 + pxi[k]) * 3 + 2] = acc[2][k];
        }
    }
    __syncthreads();
    if (seg >= 8) {                           // unique writer per slot
        #pragma unroll
        for (int k = 0; k < 4; ++k) {
            pool[((seg - 8) * 256 + pxi[k]) * 3 + 0] += acc[0][k];
            pool[((seg - 8) * 256 + pxi[k]) * 3 + 1] += acc[1][k];
            pool[((seg - 8) * 256 + pxi[k]) * 3 + 2] += acc[2][k];
        }
    }
    __syncthreads();
    if (tid < 256 * 3) {
        const int p  = tid / 3;
        const int ch = tid - 3 * p;
        float v = 0.0f;
        #pragma unroll
        for (int s = 0; s < 8; ++s) v += pool[(s * 256 + p) * 3 + ch];
        const int x = blockIdx.x * TILE_SZ + (p >> 4);
        const int y = blockIdx.y * TILE_SZ + (p & 15);
        out[(x * HEIGHT + y) * 3 + ch] = v;
    }
}

extern "C" void kernel_launch(void* const* d_in, const int* in_sizes, int n_in,
                              void* d_out, int out_size, void* d_ws, size_t ws_size,
                              hipStream_t stream) {
    const float* pts  = (const float*)d_in[0];
    const float* icov = (const float*)d_in[1];
    const float* rad  = (const float*)d_in[2];
    const float* cols = (const float*)d_in[3];
    const float* opac = (const float*)d_in[4];
    float* out = (float*)d_out;
    dim3 grid(WIDTH / TILE_SZ, HEIGHT / TILE_SZ);   // 1 block per tile
    raster_kernel<<<grid, dim3(BLK), 0, stream>>>(pts, icov, rad, cols, opac, out);
}